// Round 8
// baseline (113.260 us; speedup 1.0000x reference)
//
#include <hip/hip_runtime.h>

// Problem constants (from reference)
#define B_  64
#define T_  288
#define V_  24
#define D_  256
#define TOD_DIM 128
#define DOW_DIM 32
#define DOM_DIM 32
#define DOY_DIM 64

typedef float f32x4 __attribute__((ext_vector_type(4)));

// One block per (b,t), 256 threads, NO LDS, NO barrier, NO load hoisting.
// Each thread owns float4 column d = (tid&63)*4 and walks v = it*4 + (tid>>6).
// pos float4 comes straight from the owning table (segment bounds 128/160/192
// are float4-aligned). The fan-out loop is kept serial (#pragma unroll 1) so
// the compiler cannot hoist all loads into registers (the R5/R7 failure mode):
// per iteration just {w4,b4,x loads -> fma -> store}, ~32 VGPRs, waves ramp
// and drain independently -- no block-wide convoy stall.
__global__ __launch_bounds__(256) void input_emb_kernel(
    const float* __restrict__ features,    // (B,T,V)
    const int*   __restrict__ bar_in_day,  // (B,T)
    const int*   __restrict__ day_of_week, // (B,)
    const int*   __restrict__ day_of_month,// (B,)
    const int*   __restrict__ day_of_year, // (B,)
    const float* __restrict__ W,           // (V,D)
    const float* __restrict__ bias,        // (V,D)
    const float* __restrict__ tod_table,   // (288,128)
    const float* __restrict__ dow_table,   // (7,32)
    const float* __restrict__ dom_table,   // (32,32)
    const float* __restrict__ doy_table,   // (367,64)
    float* __restrict__ out)               // (B,T,V,D)
{
    const int bt  = blockIdx.x;
    const int b   = bt / T_;
    const int tid = threadIdx.x;
    const int q   = tid >> 6;          // wave index 0..3
    const int d   = (tid & 63) << 2;   // starting d (multiple of 4)

    // ---- per-thread pos fragment: one gather from the owning table ----
    const float* p = tod_table + bar_in_day[bt] * TOD_DIM + d;
    if (d >= TOD_DIM)
        p = dow_table + day_of_week[b] * DOW_DIM + (d - TOD_DIM);
    if (d >= TOD_DIM + DOW_DIM)
        p = dom_table + day_of_month[b] * DOM_DIM + (d - TOD_DIM - DOW_DIM);
    if (d >= TOD_DIM + DOW_DIM + DOM_DIM)
        p = doy_table + day_of_year[b] * DOY_DIM + (d - TOD_DIM - DOW_DIM - DOM_DIM);
    const f32x4 p4 = *reinterpret_cast<const f32x4*>(p);

    const float* fx  = features + bt * V_;
    float* outbt = out + (size_t)bt * (V_ * D_);

    // ---- serial fan-out loop: loads stay IN the loop ----
    #pragma unroll 1
    for (int it = 0; it < V_ / 4; ++it) {
        const int v = it * 4 + q;                  // wave-uniform
        const float x  = fx[v];
        const f32x4 w4 = *reinterpret_cast<const f32x4*>(W    + (v << 8) + d);
        const f32x4 b4 = *reinterpret_cast<const f32x4*>(bias + (v << 8) + d);
        f32x4 o;
        o.x = fmaf(x, w4.x, b4.x) + p4.x;
        o.y = fmaf(x, w4.y, b4.y) + p4.y;
        o.z = fmaf(x, w4.z, b4.z) + p4.z;
        o.w = fmaf(x, w4.w, b4.w) + p4.w;
        *reinterpret_cast<f32x4*>(outbt + (v << 8) + d) = o;
    }
}

extern "C" void kernel_launch(void* const* d_in, const int* in_sizes, int n_in,
                              void* d_out, int out_size, void* d_ws, size_t ws_size,
                              hipStream_t stream) {
    const float* features     = (const float*)d_in[0];
    const int*   bar_in_day   = (const int*)d_in[1];
    const int*   day_of_week  = (const int*)d_in[2];
    const int*   day_of_month = (const int*)d_in[3];
    const int*   day_of_year  = (const int*)d_in[4];
    const float* W            = (const float*)d_in[5];
    const float* bias         = (const float*)d_in[6];
    const float* tod_table    = (const float*)d_in[7];
    const float* dow_table    = (const float*)d_in[8];
    const float* dom_table    = (const float*)d_in[9];
    const float* doy_table    = (const float*)d_in[10];
    float* out = (float*)d_out;

    dim3 grid(B_ * T_);   // 18432 blocks
    dim3 block(256);
    input_emb_kernel<<<grid, block, 0, stream>>>(
        features, bar_in_day, day_of_week, day_of_month, day_of_year,
        W, bias, tod_table, dow_table, dom_table, doy_table, out);
}

// Round 9
// 92.069 us; speedup vs baseline: 1.2302x; 1.2302x over previous
//
#include <hip/hip_runtime.h>

// Problem constants (from reference)
#define B_  64
#define T_  288
#define V_  24
#define D_  256
#define TOD_DIM 128
#define DOW_DIM 32
#define DOM_DIM 32
#define DOY_DIM 64
#define BTPB 4   // 4 | 288 so all 4 bt share the same b

typedef float f32x4 __attribute__((ext_vector_type(4)));

// Clean ramp-amortization test: R1's phase-2 body exactly, repeated serially for
// 4 bt per block (j outer, #pragma unroll 1 -> no register blow-up, stores stay
// block-linear within each bt region). One barrier per block instead of one per bt.
// No nt stores, no register staging -- the two confounds of R3/R4.
__global__ __launch_bounds__(256) void input_emb_kernel(
    const float* __restrict__ features,    // (B,T,V)
    const int*   __restrict__ bar_in_day,  // (B,T)
    const int*   __restrict__ day_of_week, // (B,)
    const int*   __restrict__ day_of_month,// (B,)
    const int*   __restrict__ day_of_year, // (B,)
    const float* __restrict__ W,           // (V,D)
    const float* __restrict__ bias,        // (V,D)
    const float* __restrict__ tod_table,   // (288,128)
    const float* __restrict__ dow_table,   // (7,32)
    const float* __restrict__ dom_table,   // (32,32)
    const float* __restrict__ doy_table,   // (367,64)
    float* __restrict__ out)               // (B,T,V,D)
{
    __shared__ __align__(16) float pos[BTPB][D_];
    __shared__ float feats[BTPB][V_];

    const int bt0 = blockIdx.x * BTPB;
    const int b   = bt0 / T_;          // shared by all BTPB (BTPB | T_)
    const int tid = threadIdx.x;

    // ---- Phase 1: compose positional vectors for the 4 bt ----
    if (tid < TOD_DIM) {
        #pragma unroll
        for (int j = 0; j < BTPB; ++j)
            pos[j][tid] = tod_table[bar_in_day[bt0 + j] * TOD_DIM + tid];
    } else {
        float p;
        if (tid < TOD_DIM + DOW_DIM) {
            p = dow_table[day_of_week[b] * DOW_DIM + (tid - TOD_DIM)];
        } else if (tid < TOD_DIM + DOW_DIM + DOM_DIM) {
            p = dom_table[day_of_month[b] * DOM_DIM + (tid - TOD_DIM - DOW_DIM)];
        } else {
            p = doy_table[day_of_year[b] * DOY_DIM + (tid - TOD_DIM - DOW_DIM - DOM_DIM)];
        }
        #pragma unroll
        for (int j = 0; j < BTPB; ++j)
            pos[j][tid] = p;           // per-b tables: identical for all 4 t
    }
    if (tid < BTPB * V_) {             // 96 feature scalars
        feats[tid / V_][tid % V_] = features[bt0 * V_ + tid];
    }
    __syncthreads();

    // ---- Phase 2: R1's store body, serially per bt (block-linear stores) ----
    #pragma unroll 1
    for (int j = 0; j < BTPB; ++j) {
        float* outbt = out + (size_t)(bt0 + j) * (V_ * D_);
        #pragma unroll
        for (int it = 0; it < (V_ * D_ / 4) / 256; ++it) {   // 6 iterations
            const int idx = it * 256 + tid;     // float4 index within (V,D)
            const int v   = idx >> 6;           // wave-uniform
            const int d4  = idx & 63;

            const float x = feats[j][v];
            const f32x4 w4 = *reinterpret_cast<const f32x4*>(W    + (v << 8) + (d4 << 2));
            const f32x4 b4 = *reinterpret_cast<const f32x4*>(bias + (v << 8) + (d4 << 2));
            const f32x4 p4 = *reinterpret_cast<const f32x4*>(&pos[j][d4 << 2]);

            f32x4 o;
            o.x = fmaf(x, w4.x, b4.x) + p4.x;
            o.y = fmaf(x, w4.y, b4.y) + p4.y;
            o.z = fmaf(x, w4.z, b4.z) + p4.z;
            o.w = fmaf(x, w4.w, b4.w) + p4.w;

            *reinterpret_cast<f32x4*>(outbt + (idx << 2)) = o;
        }
    }
}

extern "C" void kernel_launch(void* const* d_in, const int* in_sizes, int n_in,
                              void* d_out, int out_size, void* d_ws, size_t ws_size,
                              hipStream_t stream) {
    const float* features     = (const float*)d_in[0];
    const int*   bar_in_day   = (const int*)d_in[1];
    const int*   day_of_week  = (const int*)d_in[2];
    const int*   day_of_month = (const int*)d_in[3];
    const int*   day_of_year  = (const int*)d_in[4];
    const float* W            = (const float*)d_in[5];
    const float* bias         = (const float*)d_in[6];
    const float* tod_table    = (const float*)d_in[7];
    const float* dow_table    = (const float*)d_in[8];
    const float* dom_table    = (const float*)d_in[9];
    const float* doy_table    = (const float*)d_in[10];
    float* out = (float*)d_out;

    dim3 grid((B_ * T_) / BTPB);   // 4608 blocks
    dim3 block(256);
    input_emb_kernel<<<grid, block, 0, stream>>>(
        features, bar_in_day, day_of_week, day_of_month, day_of_year,
        W, bias, tod_table, dow_table, dom_table, doy_table, out);
}